// Round 1
// baseline (292.536 us; speedup 1.0000x reference)
//
#include <hip/hip_runtime.h>
#include <math.h>

#define B_   32
#define L_   4096
#define IN_  1024
#define QS_  64
#define VS_  256
#define H_   16
#define NCH_ 16
#define CL_  256   // L_ / NCH_

// workspace layout (float offsets)
#define Q_OFF   0                       // q: [B][1024]           = 32768
#define M_OFF   32768                   // m: [B][NCH][H]         = 8192
#define S_OFF   40960                   // s: [B][NCH][H]         = 8192
#define CTX_OFF 49152                   // ctx: [B][NCH][H][VS]   = 2097152
// total = 2146304 floats = 8.59 MB

__device__ __forceinline__ float dot4(float4 a, float4 b) {
    return a.x*b.x + a.y*b.y + a.z*b.z + a.w*b.w;
}

// ---------------------------------------------------------------------------
// Kernel A: q[b,c] = (query[b,:] . Wq[c,:] + bq[c]) / 8
// grid 256 blocks x 128 thr: block owns 4 output cols, thread = (col, b)
// ---------------------------------------------------------------------------
__global__ __launch_bounds__(128) void qproj_kernel(
        const float* __restrict__ query, const float* __restrict__ Wq,
        const float* __restrict__ bq, float* __restrict__ ws) {
    const int t = threadIdx.x;
    const int c = blockIdx.x * 4 + (t >> 5);
    const int b = t & 31;
    const float4* wq4 = (const float4*)(Wq + (size_t)c * IN_);
    const float4* q4  = (const float4*)(query + (size_t)b * IN_);
    float4 acc = make_float4(0.f, 0.f, 0.f, 0.f);
    #pragma unroll 8
    for (int k = 0; k < IN_ / 4; ++k) {
        float4 w = wq4[k], q = q4[k];
        acc.x += w.x * q.x; acc.y += w.y * q.y;
        acc.z += w.z * q.z; acc.w += w.w * q.w;
    }
    float r = acc.x + acc.y + acc.z + acc.w + bq[c];
    ws[Q_OFF + b * 1024 + c] = r * 0.125f;   // fold 1/sqrt(64)
}

// ---------------------------------------------------------------------------
// Kernel B: per (b, chunk): scores for all 16 heads, chunk-local softmax,
// unnormalized ctx partial. grid (NCH_, B_) x 256 thr.
// ---------------------------------------------------------------------------
__global__ __launch_bounds__(256) void attn_chunk_kernel(
        const float* __restrict__ key, const float* __restrict__ value,
        float* __restrict__ ws) {
    __shared__ float4 qs4[256];                    // q[h][e] as float4, idx h*16+e4
    __shared__ float4 ps4[CL_ * 4];                // p[l][hq] : hq-th float4 = h 4hq..4hq+3
    __shared__ float  m_s[H_];
    __shared__ __align__(16) float scratch[8192];  // red[16][260] then cbuf[2][16][256]

    const int t  = threadIdx.x;
    const int ch = blockIdx.x, b = blockIdx.y;
    const int lm = t & 63, hq = t >> 6;            // hq == wave id
    const int l0 = ch * CL_;

    // stage q (bias+scale already folded)
    qs4[t] = ((const float4*)(ws + Q_OFF + (size_t)b * 1024))[t];
    __syncthreads();

    // ---- Phase A: scores. thread owns l = 4*lm+j (j<4), h = hq*4+hh (hh<4)
    const float* keyb = key + ((size_t)b * L_ + l0) * QS_;
    float s[4][4];
    #pragma unroll
    for (int j = 0; j < 4; ++j)
        #pragma unroll
        for (int hh = 0; hh < 4; ++hh) s[j][hh] = 0.f;

    #pragma unroll
    for (int e4 = 0; e4 < 16; ++e4) {
        float4 qv[4];
        #pragma unroll
        for (int hh = 0; hh < 4; ++hh) qv[hh] = qs4[(hq * 4 + hh) * 16 + e4];
        #pragma unroll
        for (int j = 0; j < 4; ++j) {
            float4 kv = *(const float4*)(keyb + (size_t)(4 * lm + j) * QS_ + e4 * 4);
            #pragma unroll
            for (int hh = 0; hh < 4; ++hh) s[j][hh] += dot4(kv, qv[hh]);
        }
    }

    // scores -> red[h][260] (transposed for reduction)
    float* red = scratch;
    #pragma unroll
    for (int j = 0; j < 4; ++j)
        #pragma unroll
        for (int hh = 0; hh < 4; ++hh)
            red[(hq * 4 + hh) * 260 + 4 * lm + j] = s[j][hh];
    __syncthreads();

    // chunk max per head; wave hq reduces h = hq*4+r
    float* m_ws = ws + M_OFF;
    #pragma unroll
    for (int r = 0; r < 4; ++r) {
        int h = hq * 4 + r;
        float v = red[h * 260 + lm];
        v = fmaxf(v, red[h * 260 + 64 + lm]);
        v = fmaxf(v, red[h * 260 + 128 + lm]);
        v = fmaxf(v, red[h * 260 + 192 + lm]);
        #pragma unroll
        for (int off = 32; off >= 1; off >>= 1) v = fmaxf(v, __shfl_xor(v, off));
        if (lm == 0) { m_s[h] = v; m_ws[(b * NCH_ + ch) * H_ + h] = v; }
    }
    __syncthreads();

    // p = exp(s - m); store for phase B ([l][h] float4-packed) and for sum-reduce
    float p[4][4];
    #pragma unroll
    for (int j = 0; j < 4; ++j)
        #pragma unroll
        for (int hh = 0; hh < 4; ++hh)
            p[j][hh] = __expf(s[j][hh] - m_s[hq * 4 + hh]);
    #pragma unroll
    for (int j = 0; j < 4; ++j)
        ps4[(4 * lm + j) * 4 + hq] = make_float4(p[j][0], p[j][1], p[j][2], p[j][3]);
    #pragma unroll
    for (int j = 0; j < 4; ++j)
        #pragma unroll
        for (int hh = 0; hh < 4; ++hh)
            red[(hq * 4 + hh) * 260 + 4 * lm + j] = p[j][hh];
    __syncthreads();

    // chunk sum per head
    float* s_ws = ws + S_OFF;
    #pragma unroll
    for (int r = 0; r < 4; ++r) {
        int h = hq * 4 + r;
        float v = red[h * 260 + lm] + red[h * 260 + 64 + lm]
                + red[h * 260 + 128 + lm] + red[h * 260 + 192 + lm];
        #pragma unroll
        for (int off = 32; off >= 1; off >>= 1) v += __shfl_xor(v, off);
        if (lm == 0) s_ws[(b * NCH_ + ch) * H_ + h] = v;
    }

    // ---- Phase B: ctx[h][e] += p[l][h] * value[l][e]
    // wave hq owns l = hq*64+i; lane lm owns e = 4*lm..4*lm+3 (coalesced 1KB/wave)
    float ctx[16][4];
    #pragma unroll
    for (int h = 0; h < 16; ++h)
        #pragma unroll
        for (int jj = 0; jj < 4; ++jj) ctx[h][jj] = 0.f;

    const float* valb = value + ((size_t)b * L_ + l0) * VS_;
    for (int i = 0; i < 64; ++i) {
        int l = hq * 64 + i;
        float4 v = *(const float4*)(valb + (size_t)l * VS_ + lm * 4);
        float4 pA = ps4[l * 4 + 0], pB = ps4[l * 4 + 1];
        float4 pC = ps4[l * 4 + 2], pD = ps4[l * 4 + 3];
        float pp[16] = {pA.x, pA.y, pA.z, pA.w, pB.x, pB.y, pB.z, pB.w,
                        pC.x, pC.y, pC.z, pC.w, pD.x, pD.y, pD.z, pD.w};
        #pragma unroll
        for (int h = 0; h < 16; ++h) {
            ctx[h][0] += pp[h] * v.x; ctx[h][1] += pp[h] * v.y;
            ctx[h][2] += pp[h] * v.z; ctx[h][3] += pp[h] * v.w;
        }
    }
    __syncthreads();   // red reads + ps4 reads done everywhere; scratch reusable

    // reduce the 4 wave-partials: waves 0,1 write; waves 2,3 accumulate
    float4* cb4 = (float4*)scratch;   // [2][16][64] float4
    if (hq < 2) {
        #pragma unroll
        for (int h = 0; h < 16; ++h)
            cb4[(hq * 16 + h) * 64 + lm] =
                make_float4(ctx[h][0], ctx[h][1], ctx[h][2], ctx[h][3]);
    }
    __syncthreads();
    if (hq >= 2) {
        #pragma unroll
        for (int h = 0; h < 16; ++h) {
            float4 o = cb4[((hq - 2) * 16 + h) * 64 + lm];
            o.x += ctx[h][0]; o.y += ctx[h][1];
            o.z += ctx[h][2]; o.w += ctx[h][3];
            cb4[((hq - 2) * 16 + h) * 64 + lm] = o;
        }
    }
    __syncthreads();

    float* ctxw = ws + CTX_OFF + (size_t)(b * NCH_ + ch) * H_ * VS_;
    #pragma unroll
    for (int k = 0; k < 16; ++k) {
        int c = k * 256 + t;        // c = h*256 + e
        ctxw[c] = scratch[c] + scratch[4096 + c];
    }
}

// ---------------------------------------------------------------------------
// Kernel C: combine chunk partials (flash-style) + project with Wv + bias.
// grid B_*H_ blocks x 256 thr.
// ---------------------------------------------------------------------------
__global__ __launch_bounds__(256) void reduce_proj_kernel(
        const float* __restrict__ Wv, const float* __restrict__ bv,
        const float* __restrict__ ws, float* __restrict__ out) {
    __shared__ __align__(16) float ctx_lds[VS_];
    const int t = threadIdx.x;
    const int b = blockIdx.x >> 4, h = blockIdx.x & 15;
    const float* m_ws   = ws + M_OFF;
    const float* s_ws   = ws + S_OFF;
    const float* ctx_ws = ws + CTX_OFF;

    float mc[16], wc[16];
    float M = -1e30f;
    #pragma unroll
    for (int c = 0; c < 16; ++c) {
        mc[c] = m_ws[(b * 16 + c) * 16 + h];
        M = fmaxf(M, mc[c]);
    }
    float S = 0.f;
    #pragma unroll
    for (int c = 0; c < 16; ++c) {
        float w = __expf(mc[c] - M);
        wc[c] = w;
        S += s_ws[(b * 16 + c) * 16 + h] * w;
    }
    const float inv = 1.f / S;

    float acc = 0.f;
    #pragma unroll
    for (int c = 0; c < 16; ++c)
        acc += wc[c] * ctx_ws[((size_t)(b * 16 + c) * 16 + h) * VS_ + t];
    ctx_lds[t] = acc * inv;
    __syncthreads();

    const int d = t >> 2, qq = t & 3;
    const float4* wv4 = (const float4*)(Wv + (size_t)(h * 64 + d) * VS_);
    const float4* cl4 = (const float4*)ctx_lds;
    float a = 0.f;
    #pragma unroll
    for (int i = 0; i < 16; ++i) a += dot4(wv4[qq * 16 + i], cl4[qq * 16 + i]);
    a += __shfl_xor(a, 1);
    a += __shfl_xor(a, 2);
    if (qq == 0) out[b * 1024 + h * 64 + d] = a + bv[h * 64 + d];
}

extern "C" void kernel_launch(void* const* d_in, const int* in_sizes, int n_in,
                              void* d_out, int out_size, void* d_ws, size_t ws_size,
                              hipStream_t stream) {
    (void)in_sizes; (void)n_in; (void)out_size; (void)ws_size;
    const float* query = (const float*)d_in[0];
    const float* key   = (const float*)d_in[1];
    const float* value = (const float*)d_in[2];
    const float* Wq    = (const float*)d_in[3];
    const float* bq    = (const float*)d_in[4];
    const float* Wv    = (const float*)d_in[5];
    const float* bv    = (const float*)d_in[6];
    float* out = (float*)d_out;
    float* ws  = (float*)d_ws;

    qproj_kernel<<<256, 128, 0, stream>>>(query, Wq, bq, ws);
    attn_chunk_kernel<<<dim3(NCH_, B_), 256, 0, stream>>>(key, value, ws);
    reduce_proj_kernel<<<B_ * H_, 256, 0, stream>>>(Wv, bv, ws, out);
}

// Round 2
// 289.217 us; speedup vs baseline: 1.0115x; 1.0115x over previous
//
#include <hip/hip_runtime.h>
#include <math.h>

#define B_   32
#define L_   4096
#define IN_  1024
#define QS_  64
#define VS_  256
#define H_   16

#define Q_OFF 0
#define M_OFF 32768

__device__ __forceinline__ float dot4(float4 a, float4 b) {
    return a.x*b.x + a.y*b.y + a.z*b.z + a.w*b.w;
}

// ---------------------------------------------------------------------------
// Kernel A: q[b,c] = (query[b,:] . Wq[c,:] + bq[c]) / 8
// 512 blocks x 256 thr; 4 threads per output (k-split), shfl combine.
// ---------------------------------------------------------------------------
__global__ __launch_bounds__(256) void qproj_kernel(
        const float* __restrict__ query, const float* __restrict__ Wq,
        const float* __restrict__ bq, float* __restrict__ ws) {
    const int t = threadIdx.x;
    const int g = blockIdx.x * 256 + t;
    const int o = g >> 2, sub = g & 3;        // sub == t&3 (lane-group aligned)
    const int b = o >> 10, c = o & 1023;

    const float4* wq4 = (const float4*)(Wq + (size_t)c * IN_) + sub * 64;
    const float4* q4  = (const float4*)(query + (size_t)b * IN_) + sub * 64;
    float4 acc = make_float4(0.f, 0.f, 0.f, 0.f);
    #pragma unroll 8
    for (int k = 0; k < 64; ++k) {
        float4 w = wq4[k], q = q4[k];
        acc.x += w.x * q.x; acc.y += w.y * q.y;
        acc.z += w.z * q.z; acc.w += w.w * q.w;
    }
    float r = acc.x + acc.y + acc.z + acc.w;
    r += __shfl_xor(r, 1);
    r += __shfl_xor(r, 2);
    if (sub == 0) ws[Q_OFF + b * 1024 + c] = (r + bq[c]) * 0.125f;
}

// ---------------------------------------------------------------------------
// Kernel B: per (b, chunk of CL rows): wave w owns heads 4w..4w+3 over ALL
// rows. Softmax reductions are wave-local shfl; no cross-wave ctx reduce.
// ---------------------------------------------------------------------------
template<int CL>
__global__ __launch_bounds__(256, 4) void attn_chunk_kernel(
        const float* __restrict__ key, const float* __restrict__ value,
        float* __restrict__ ws) {
    constexpr int NCH = L_ / CL;
    constexpr int R   = CL / 64;                    // rows per thread (phase A)
    constexpr int S_OFF   = M_OFF + B_ * NCH * H_;
    constexpr int CTX_OFF = S_OFF + B_ * NCH * H_;

    __shared__ float4 qs4[256];                     // q[h][e4]
    __shared__ float4 ps4[4 * CL];                  // per-wave [CL] of 4-head p

    const int t  = threadIdx.x;
    const int ch = blockIdx.x, b = blockIdx.y;
    const int lm = t & 63, w = t >> 6;
    const int l0 = ch * CL;

    qs4[t] = ((const float4*)(ws + Q_OFF + (size_t)b * IN_))[t];
    __syncthreads();

    // ---- Phase A: scores. lane owns rows R*lm+j, wave's 4 heads.
    const float* keyb = key + ((size_t)b * L_ + l0) * QS_;
    float s[R][4];
    #pragma unroll
    for (int j = 0; j < R; ++j)
        #pragma unroll
        for (int hh = 0; hh < 4; ++hh) s[j][hh] = 0.f;

    #pragma unroll
    for (int e4 = 0; e4 < 16; ++e4) {
        float4 qv[4];
        #pragma unroll
        for (int hh = 0; hh < 4; ++hh) qv[hh] = qs4[(4 * w + hh) * 16 + e4];
        #pragma unroll
        for (int j = 0; j < R; ++j) {
            float4 kv = *(const float4*)(keyb + (size_t)(R * lm + j) * QS_ + e4 * 4);
            #pragma unroll
            for (int hh = 0; hh < 4; ++hh) s[j][hh] += dot4(kv, qv[hh]);
        }
    }

    // wave-local max per head
    float m[4];
    #pragma unroll
    for (int hh = 0; hh < 4; ++hh) {
        float v = s[0][hh];
        #pragma unroll
        for (int j = 1; j < R; ++j) v = fmaxf(v, s[j][hh]);
        #pragma unroll
        for (int off = 32; off >= 1; off >>= 1) v = fmaxf(v, __shfl_xor(v, off));
        m[hh] = v;
    }

    // p = exp(s - m), wave-local sum per head
    float p[R][4];
    #pragma unroll
    for (int j = 0; j < R; ++j)
        #pragma unroll
        for (int hh = 0; hh < 4; ++hh) p[j][hh] = __expf(s[j][hh] - m[hh]);

    float sum[4];
    #pragma unroll
    for (int hh = 0; hh < 4; ++hh) {
        float v = p[0][hh];
        #pragma unroll
        for (int j = 1; j < R; ++j) v += p[j][hh];
        #pragma unroll
        for (int off = 32; off >= 1; off >>= 1) v += __shfl_xor(v, off);
        sum[hh] = v;
    }
    if (lm == 0) {
        #pragma unroll
        for (int hh = 0; hh < 4; ++hh) {
            ws[M_OFF + (b * NCH + ch) * H_ + 4 * w + hh] = m[hh];
            ws[S_OFF + (b * NCH + ch) * H_ + 4 * w + hh] = sum[hh];
        }
    }

    // stash p for phase B (wave-local region; no barrier needed)
    #pragma unroll
    for (int j = 0; j < R; ++j)
        ps4[w * CL + R * lm + j] = make_float4(p[j][0], p[j][1], p[j][2], p[j][3]);

    // ---- Phase B: ctx[hh][e] = sum_l p[l][hh] * value[l][e]
    // lane owns e = 4*lm..4*lm+3; wave streams ALL CL rows. 8-deep load batch.
    float4 ctx[4];
    #pragma unroll
    for (int hh = 0; hh < 4; ++hh) ctx[hh] = make_float4(0.f, 0.f, 0.f, 0.f);

    const float*  valb = value + ((size_t)b * L_ + l0) * VS_;
    const float4* psw  = ps4 + w * CL;
    for (int i0 = 0; i0 < CL; i0 += 8) {
        float4 vv[8], pv[8];
        #pragma unroll
        for (int u = 0; u < 8; ++u)
            vv[u] = *(const float4*)(valb + (size_t)(i0 + u) * VS_ + 4 * lm);
        #pragma unroll
        for (int u = 0; u < 8; ++u) pv[u] = psw[i0 + u];
        #pragma unroll
        for (int u = 0; u < 8; ++u) {
            const float* ph = (const float*)&pv[u];
            #pragma unroll
            for (int hh = 0; hh < 4; ++hh) {
                ctx[hh].x += ph[hh] * vv[u].x;
                ctx[hh].y += ph[hh] * vv[u].y;
                ctx[hh].z += ph[hh] * vv[u].z;
                ctx[hh].w += ph[hh] * vv[u].w;
            }
        }
    }

    float* ctxw = ws + CTX_OFF + (size_t)((b * NCH + ch) * H_) * VS_;
    #pragma unroll
    for (int hh = 0; hh < 4; ++hh)
        *(float4*)(ctxw + (size_t)(4 * w + hh) * VS_ + 4 * lm) = ctx[hh];
}

// ---------------------------------------------------------------------------
// Kernel C: flash-combine chunk partials + project with Wv + bias.
// ---------------------------------------------------------------------------
template<int CL>
__global__ __launch_bounds__(256) void reduce_proj_kernel(
        const float* __restrict__ Wv, const float* __restrict__ bv,
        const float* __restrict__ ws, float* __restrict__ out) {
    constexpr int NCH = L_ / CL;
    constexpr int S_OFF   = M_OFF + B_ * NCH * H_;
    constexpr int CTX_OFF = S_OFF + B_ * NCH * H_;

    __shared__ __align__(16) float ctx_lds[VS_];
    const int t = threadIdx.x;
    const int b = blockIdx.x >> 4, h = blockIdx.x & 15;

    float M = -1e30f;
    #pragma unroll
    for (int c = 0; c < NCH; ++c)
        M = fmaxf(M, ws[M_OFF + (b * NCH + c) * H_ + h]);

    float S = 0.f, acc = 0.f;
    #pragma unroll 4
    for (int c = 0; c < NCH; ++c) {
        float wgt = __expf(ws[M_OFF + (b * NCH + c) * H_ + h] - M);
        S += ws[S_OFF + (b * NCH + c) * H_ + h] * wgt;
        acc += wgt * ws[CTX_OFF + ((size_t)(b * NCH + c) * H_ + h) * VS_ + t];
    }
    ctx_lds[t] = acc / S;
    __syncthreads();

    const int d = t >> 2, qq = t & 3;
    const float4* wv4 = (const float4*)(Wv + (size_t)(h * 64 + d) * VS_);
    const float4* cl4 = (const float4*)ctx_lds;
    float a = 0.f;
    #pragma unroll
    for (int i = 0; i < 16; ++i) a += dot4(wv4[qq * 16 + i], cl4[qq * 16 + i]);
    a += __shfl_xor(a, 1);
    a += __shfl_xor(a, 2);
    if (qq == 0) out[b * 1024 + h * 64 + d] = a + bv[h * 64 + d];
}

extern "C" void kernel_launch(void* const* d_in, const int* in_sizes, int n_in,
                              void* d_out, int out_size, void* d_ws, size_t ws_size,
                              hipStream_t stream) {
    (void)in_sizes; (void)n_in; (void)out_size;
    const float* query = (const float*)d_in[0];
    const float* key   = (const float*)d_in[1];
    const float* value = (const float*)d_in[2];
    const float* Wq    = (const float*)d_in[3];
    const float* bq    = (const float*)d_in[4];
    const float* Wv    = (const float*)d_in[5];
    const float* bv    = (const float*)d_in[6];
    float* out = (float*)d_out;
    float* ws  = (float*)d_ws;

    qproj_kernel<<<512, 256, 0, stream>>>(query, Wq, bq, ws);

    // CL=128 needs ws >= (32768 q + 2*16384 m/s + 4194304 ctx) floats = ~17.04 MB
    const size_t need128 = (size_t)(32768 + 2 * B_ * 32 * H_ + (size_t)B_ * 32 * H_ * VS_) * 4;
    if (ws_size >= need128) {
        attn_chunk_kernel<128><<<dim3(32, B_), 256, 0, stream>>>(key, value, ws);
        reduce_proj_kernel<128><<<B_ * H_, 256, 0, stream>>>(Wv, bv, ws, out);
    } else {
        attn_chunk_kernel<256><<<dim3(16, B_), 256, 0, stream>>>(key, value, ws);
        reduce_proj_kernel<256><<<B_ * H_, 256, 0, stream>>>(Wv, bv, ws, out);
    }
}